// Round 12
// baseline (1429.397 us; speedup 1.0000x reference)
//
#include <hip/hip_runtime.h>
#include <math.h>

#define NODES_TOTAL 160000
#define NODES_REAL  5000
#define D 128
#define NEG 0.2f
#define KP2 128
#define HL2 (128 * KP2)       // ushorts per hi (or lo) block = 16384
#define WT2_L (2 * HL2)       // ushorts per layer (hi + lo)  = 32768 (64 KB)
#define CHUNK 16384           // edges per CSR chunk (2^14)
#define MEGA_NB 1024          // persistent blocks (4/CU guaranteed by launch_bounds)

typedef unsigned short ushort_t;
typedef unsigned int uint_t;
typedef __attribute__((ext_vector_type(8))) __bf16 bf16x8;
typedef __attribute__((ext_vector_type(4))) float f32x4;
union BF8 { bf16x8 v; ushort_t u[8]; };

__device__ __forceinline__ void split2(float x, ushort_t& hi, ushort_t& lo) {
    unsigned u = __float_as_uint(x);
    hi = (ushort_t)(u >> 16);
    float hif = __uint_as_float(u & 0xffff0000u);
    lo = (ushort_t)(__float_as_uint(x - hif) >> 16);
}
__device__ __forceinline__ uint_t encmax(float f) {
    uint_t b = __float_as_uint(f);
    return b ^ ((uint_t)((int)b >> 31) | 0x80000000u);
}
__device__ __forceinline__ float decmax(uint_t u) {
    uint_t b = (u & 0x80000000u) ? (u ^ 0x80000000u) : ~u;
    return __uint_as_float(b);
}

// device-scope grid barrier: valid because grid <= guaranteed co-resident blocks
__device__ __forceinline__ void grid_sync(uint_t* cnt, uint_t target) {
    __syncthreads();
    if (threadIdx.x == 0) {
        __threadfence();                       // release
        atomicAdd(cnt, 1u);                    // device scope by default
        while (*(volatile uint_t*)cnt < target) __builtin_amdgcn_s_sleep(2);
        __threadfence();                       // acquire (invalidates CU L1)
    }
    __syncthreads();
}

// ---------------- W split (frag-major) + ALL workspace zeroing -----------------
__global__ void wsplit_kernel(const float* __restrict__ Ws, ushort_t* __restrict__ Wm,
                              int* __restrict__ counts, uint_t* __restrict__ gmaxu,
                              uint_t* __restrict__ sync_cnt) {
    int gid = blockIdx.x * 256 + threadIdx.x;
    if (gid < NODES_REAL) counts[gid] = 0;
    if (gid < 3) gmaxu[gid] = 0u;
    if (gid == 3) *sync_cnt = 0u;
    int l  = blockIdx.x >> 3;
    int n  = (blockIdx.x & 7) * 16 + (threadIdx.x >> 4);
    int c8 = threadIdx.x & 15;
    int k0 = c8 * 8;
    const float* src = Ws + (size_t)l * D * D;
    union { ushort_t u[8]; uint4 v; } hi, lo;
    #pragma unroll
    for (int j = 0; j < 8; ++j) split2(src[(size_t)(k0 + j) * D + n], hi.u[j], lo.u[j]);
    int ct = n >> 4, m16 = n & 15, kc = c8 >> 2, qq = c8 & 3;
    int lane = qq * 16 + m16;
    ushort_t* d2 = Wm + (size_t)l * WT2_L + ((ct * 4 + kc) * 2 + 0) * 512 + lane * 8;
    *(uint4*)d2 = hi.v;
    *(uint4*)(d2 + 512) = lo.v;     // hl=1
}

// ---------------- fused 3-layer MLP (round-4 structure, single launch) ---------
__global__ __launch_bounds__(256, 2)
void mlp3_kernel(const float* __restrict__ x, const ushort_t* __restrict__ Wm,
                 const float* __restrict__ bs, float* __restrict__ out) {
    __shared__ float scr[2][2][16][132];   // 33792 B
    int tid = threadIdx.x;
    int w = tid >> 6, lane = tid & 63, q = lane >> 4, m16 = lane & 15;
    int p = w >> 1, h = w & 1;
    int row0 = NODES_REAL + blockIdx.x * 64 + p * 32;

    float4 xa[2][4][2];
    #pragma unroll
    for (int rt = 0; rt < 2; ++rt) {
        int r = row0 + rt * 16 + m16;
        if (r > NODES_TOTAL - 1) r = NODES_TOTAL - 1;
        #pragma unroll
        for (int kc = 0; kc < 4; ++kc) {
            const float* gp = x + (size_t)r * D + kc * 32 + q * 8;
            xa[rt][kc][0] = *(const float4*)gp;
            xa[rt][kc][1] = *(const float4*)(gp + 4);
        }
    }

    f32x4 acc[2][4];
    #pragma unroll
    for (int l = 0; l < 3; ++l) {
        const ushort_t* Wml = Wm + (size_t)l * WT2_L;
        if (l > 0) __syncthreads();

        BF8 ahi[2][4], alo[2][4];
        #pragma unroll
        for (int rt = 0; rt < 2; ++rt)
            #pragma unroll
            for (int kc = 0; kc < 4; ++kc) {
                float4 v0, v1;
                if (l == 0) { v0 = xa[rt][kc][0]; v1 = xa[rt][kc][1]; }
                else {
                    const float* sp = &scr[p][rt][m16][kc * 32 + q * 8];
                    v0 = *(const float4*)sp; v1 = *(const float4*)(sp + 4);
                }
                float xv[8] = {v0.x, v0.y, v0.z, v0.w, v1.x, v1.y, v1.z, v1.w};
                #pragma unroll
                for (int j = 0; j < 8; ++j) split2(xv[j], ahi[rt][kc].u[j], alo[rt][kc].u[j]);
            }
        if (l > 0) __syncthreads();

        #pragma unroll
        for (int rt = 0; rt < 2; ++rt)
            #pragma unroll
            for (int ct = 0; ct < 4; ++ct) acc[rt][ct] = (f32x4){0.f, 0.f, 0.f, 0.f};

        #pragma unroll
        for (int ph = 0; ph < 2; ++ph) {
            int kc0 = ph * 2;
            bf16x8 bh[4][2], bl[4][2];
            #pragma unroll
            for (int ct = 0; ct < 4; ++ct)
                #pragma unroll
                for (int dk = 0; dk < 2; ++dk) {
                    const ushort_t* bp = Wml + (((h * 4 + ct) * 4 + (kc0 + dk)) * 2) * 512 + lane * 8;
                    bh[ct][dk] = *(const bf16x8*)bp;
                    bl[ct][dk] = *(const bf16x8*)(bp + 512);
                }
            #pragma unroll
            for (int dk = 0; dk < 2; ++dk)
                #pragma unroll
                for (int ct = 0; ct < 4; ++ct)
                    #pragma unroll
                    for (int rt = 0; rt < 2; ++rt) {
                        acc[rt][ct] = __builtin_amdgcn_mfma_f32_16x16x32_bf16(ahi[rt][kc0 + dk].v, bh[ct][dk], acc[rt][ct], 0, 0, 0);
                        acc[rt][ct] = __builtin_amdgcn_mfma_f32_16x16x32_bf16(ahi[rt][kc0 + dk].v, bl[ct][dk], acc[rt][ct], 0, 0, 0);
                        acc[rt][ct] = __builtin_amdgcn_mfma_f32_16x16x32_bf16(alo[rt][kc0 + dk].v, bh[ct][dk], acc[rt][ct], 0, 0, 0);
                    }
        }
        float bv[4];
        #pragma unroll
        for (int ct = 0; ct < 4; ++ct) bv[ct] = bs[l * D + (h * 4 + ct) * 16 + m16];
        #pragma unroll
        for (int rt = 0; rt < 2; ++rt)
            #pragma unroll
            for (int ct = 0; ct < 4; ++ct)
                #pragma unroll
                for (int reg = 0; reg < 4; ++reg)
                    scr[p][rt][q * 4 + reg][(h * 4 + ct) * 16 + m16] =
                        fmaxf(acc[rt][ct][reg] + bv[ct], 0.f);
    }
    __syncthreads();
    #pragma unroll
    for (int i = 0; i < 8; ++i) {
        int rowl = i * 2 + (lane >> 5);
        int grow = row0 + h * 16 + rowl;
        float4 v = *(const float4*)&scr[p][h][rowl][(lane & 31) * 4];
        if (grow < NODES_TOTAL)
            *(float4*)&out[(size_t)grow * D + (lane & 31) * 4] = v;
    }
}

// ---------------- device bodies for the persistent small-pipeline kernel -------
// gsmall (register-B, slim: 4 B-pairs live at a time to fit VGPR<=128)
__device__ __forceinline__ void gsmall_wave(const float* __restrict__ hin,
        const ushort_t* __restrict__ Wml, const float* __restrict__ a_s,
        const float* __restrict__ a_d, float* __restrict__ h2,
        float* __restrict__ sv, float* __restrict__ dv, uint_t* __restrict__ gmax,
        int row0, int lane) {
    int q = lane >> 4, m16 = lane & 15;
    int rr = row0 + m16; if (rr > NODES_REAL - 1) rr = NODES_REAL - 1;
    f32x4 acc[8];
    #pragma unroll
    for (int ct = 0; ct < 8; ++ct) acc[ct] = (f32x4){0.f, 0.f, 0.f, 0.f};
    #pragma unroll
    for (int kc = 0; kc < 4; ++kc) {
        const float* gp = hin + (size_t)rr * D + kc * 32 + q * 8;
        float4 v0 = *(const float4*)gp, v1 = *(const float4*)(gp + 4);
        BF8 ahi, alo;
        {
            float xv[8] = {v0.x, v0.y, v0.z, v0.w, v1.x, v1.y, v1.z, v1.w};
            #pragma unroll
            for (int j = 0; j < 8; ++j) split2(xv[j], ahi.u[j], alo.u[j]);
        }
        #pragma unroll
        for (int cth = 0; cth < 2; ++cth) {
            bf16x8 bh[4], bl[4];
            #pragma unroll
            for (int c4 = 0; c4 < 4; ++c4) {
                int ct = cth * 4 + c4;
                const ushort_t* bp = Wml + ((ct * 4 + kc) * 2) * 512 + lane * 8;
                bh[c4] = *(const bf16x8*)bp;
                bl[c4] = *(const bf16x8*)(bp + 512);
            }
            #pragma unroll
            for (int c4 = 0; c4 < 4; ++c4) {
                int ct = cth * 4 + c4;
                acc[ct] = __builtin_amdgcn_mfma_f32_16x16x32_bf16(ahi.v, bh[c4], acc[ct], 0, 0, 0);
                acc[ct] = __builtin_amdgcn_mfma_f32_16x16x32_bf16(ahi.v, bl[c4], acc[ct], 0, 0, 0);
                acc[ct] = __builtin_amdgcn_mfma_f32_16x16x32_bf16(alo.v, bh[c4], acc[ct], 0, 0, 0);
            }
        }
    }
    #pragma unroll
    for (int reg = 0; reg < 4; ++reg) {
        int grow = row0 + q * 4 + reg;
        if (grow < NODES_REAL) {
            #pragma unroll
            for (int ct = 0; ct < 8; ++ct)
                h2[(size_t)grow * D + ct * 16 + m16] = acc[ct][reg];
        }
    }
    float asv[8], adv[8];
    #pragma unroll
    for (int ct = 0; ct < 8; ++ct) { asv[ct] = a_s[ct * 16 + m16]; adv[ct] = a_d[ct * 16 + m16]; }
    #pragma unroll
    for (int reg = 0; reg < 4; ++reg) {
        float ps = 0.f, pd = 0.f;
        #pragma unroll
        for (int ct = 0; ct < 8; ++ct) {
            float v = acc[ct][reg];
            ps += v * asv[ct]; pd += v * adv[ct];
        }
        #pragma unroll
        for (int o = 1; o < 16; o <<= 1) { ps += __shfl_xor(ps, o); pd += __shfl_xor(pd, o); }
        int grow = row0 + q * 4 + reg;
        if (m16 == 0 && grow < NODES_REAL) {
            sv[grow] = ps; dv[grow] = pd;
            atomicMax(gmax, encmax(ps));
        }
    }
}

// agg for one dst (r11-verified shfl-free 2-phase body)
__device__ __forceinline__ void agg_dst(int i, const float* __restrict__ h2,
        const float* __restrict__ sv, const float* __restrict__ dv,
        const int* __restrict__ offs, const ushort_t* __restrict__ esrc,
        const float* __restrict__ bias, float* __restrict__ hout,
        const uint_t* __restrict__ gmaxu, int w, int lane, int tid,
        float2* pair_l, float2 (*red)[64], float* lexs) {
    int start = offs[i], end = offs[i + 1];
    float d_i = dv[i];
    float gm = decmax(*gmaxu) + d_i;
    float m = gm > 0.f ? gm : NEG * gm;
    const float2* h2v = (const float2*)h2;
    float ax0 = 0.f, ay0 = 0.f, ax1 = 0.f, ay1 = 0.f;
    float ax2 = 0.f, ay2 = 0.f, ax3 = 0.f, ay3 = 0.f, exs = 0.f;
    for (int tile = start; tile < end; tile += 512) {
        int tcnt = min(512, end - tile);
        __syncthreads();                   // prior pair_l readers done
        #pragma unroll
        for (int hh = 0; hh < 2; ++hh) {
            int j = hh * 256 + tid;
            if (j < tcnt) {
                int s = (int)esrc[tile + j];
                float sc = sv[s] + d_i;
                sc = sc > 0.f ? sc : NEG * sc;
                float ex = __expf(sc - m);
                exs += ex;
                pair_l[j] = make_float2(ex, __uint_as_float((uint_t)s));
            }
        }
        __syncthreads();
        for (int j0 = w * 64; j0 < tcnt; j0 += 256) {
            int jend = min(j0 + 64, tcnt);
            int j = j0;
            for (; j + 4 <= jend; j += 4) {
                float2 p0 = pair_l[j],     p1 = pair_l[j + 1];
                float2 p2 = pair_l[j + 2], p3 = pair_l[j + 3];
                float2 v0 = h2v[(size_t)__float_as_uint(p0.y) * 64 + lane];
                float2 v1 = h2v[(size_t)__float_as_uint(p1.y) * 64 + lane];
                float2 v2 = h2v[(size_t)__float_as_uint(p2.y) * 64 + lane];
                float2 v3 = h2v[(size_t)__float_as_uint(p3.y) * 64 + lane];
                ax0 += p0.x * v0.x; ay0 += p0.x * v0.y;
                ax1 += p1.x * v1.x; ay1 += p1.x * v1.y;
                ax2 += p2.x * v2.x; ay2 += p2.x * v2.y;
                ax3 += p3.x * v3.x; ay3 += p3.x * v3.y;
            }
            for (; j < jend; ++j) {
                float2 p0 = pair_l[j];
                float2 v0 = h2v[(size_t)__float_as_uint(p0.y) * 64 + lane];
                ax0 += p0.x * v0.x; ay0 += p0.x * v0.y;
            }
        }
    }
    float ax = (ax0 + ax1) + (ax2 + ax3);
    float ay = (ay0 + ay1) + (ay2 + ay3);
    #pragma unroll
    for (int o = 1; o < 64; o <<= 1) exs += __shfl_xor(exs, o);
    __syncthreads();
    red[w][lane] = make_float2(ax, ay);
    if (lane == 0) lexs[w] = exs;
    __syncthreads();
    if (w == 0) {
        float2 r1 = red[1][lane], r2 = red[2][lane], r3 = red[3][lane];
        ax += r1.x + r2.x + r3.x;
        ay += r1.y + r2.y + r3.y;
        float exst = lexs[0] + lexs[1] + lexs[2] + lexs[3];
        float scf = sv[i] + d_i; scf = scf > 0.f ? scf : NEG * scf;
        float exf = __expf(scf - m);
        float2 hv = h2v[(size_t)i * 64 + lane];
        ax += exf * hv.x; ay += exf * hv.y;
        float rd = 1.f / (exst + exf);
        float2 b2 = *(const float2*)&bias[2 * lane];
        float2 o2 = make_float2(fmaxf(ax * rd + b2.x, 0.f), fmaxf(ay * rd + b2.y, 0.f));
        *(float2*)&hout[(size_t)i * D + 2 * lane] = o2;
    }
}

// ---------------- persistent small-pipeline kernel (CSR + 3x(gsmall,agg)) ------
// 1024 blocks, all co-resident (launch_bounds(256,4): VGPR<=128, LDS 27.2KB/blk
// -> 4 blocks/CU capacity). 7 grid-syncs replace 8 launch boundaries.
__global__ __launch_bounds__(256, 4)
void mega_kernel(const float* __restrict__ x, const ushort_t* __restrict__ Wm,
                 const float* __restrict__ as_, const float* __restrict__ ad_,
                 const float* __restrict__ bs, const int* __restrict__ ei,
                 float* __restrict__ h2, float* __restrict__ bufS,
                 float* __restrict__ sv, float* __restrict__ dv,
                 int* __restrict__ counts, int* __restrict__ offs,
                 ushort_t* __restrict__ rank16, ushort_t* __restrict__ esrc,
                 uint_t* __restrict__ gmaxu, float* __restrict__ out,
                 uint_t* __restrict__ sync_cnt, int Eh, int nchunks) {
    __shared__ uint_t lc[NODES_REAL];      // 20000 B (rank2)
    __shared__ float2 pair_l[512];         //  4096 B (agg)
    __shared__ float2 red[4][64];          //  2048 B (agg)
    __shared__ float lexs[4];              //    16 B (agg)
    __shared__ int sd2[256];               //  1024 B (scan)
    int b = blockIdx.x, tid = threadIdx.x;
    int w = tid >> 6, lane = tid & 63;
    uint_t NB = gridDim.x;
    int* bases = (int*)bufS;               // dead until agg0 writes bufS

    // P0: rank2 (blocks < nchunks) || gsmall layer0 (remaining blocks)
    if (b < nchunks) {
        for (int i2 = tid; i2 < NODES_REAL; i2 += 256) lc[i2] = 0u;
        __syncthreads();
        int e0 = b * CHUNK;
        #pragma unroll 4
        for (int k = 0; k < CHUNK / 256; ++k) {
            int e = e0 + k * 256 + tid;
            if (e < Eh) {
                int d = ei[Eh + e];
                uint_t r = atomicAdd(&lc[d], 1u);
                rank16[e] = (ushort_t)r;
            }
        }
        __syncthreads();
        for (int i2 = tid; i2 < NODES_REAL; i2 += 256) {
            uint_t n = lc[i2];
            if (n > 0u)
                bases[b * NODES_REAL + i2] = atomicAdd(&counts[i2], (int)n);
        }
    } else {
        int gw = (b - nchunks) * 4 + w;
        if (gw * 16 < NODES_REAL)
            gsmall_wave(x, Wm, as_, ad_, h2, sv, dv, gmaxu + 0, gw * 16, lane);
    }
    uint_t tgt = NB; grid_sync(sync_cnt, tgt);

    // P1: scan (block 0 only; 256 threads x 20 elements)
    if (b == 0) {
        int t = tid;
        int pre[20]; int sum = 0;
        #pragma unroll
        for (int u = 0; u < 20; ++u) {
            int idx = t * 20 + u;
            int c = (idx < NODES_REAL) ? counts[idx] : 0;
            pre[u] = sum; sum += c;
        }
        sd2[t] = sum;
        __syncthreads();
        int run = sum;
        for (int o = 1; o < 256; o <<= 1) {
            int v = (t >= o) ? sd2[t - o] : 0;
            __syncthreads();
            sd2[t] += v;
            __syncthreads();
        }
        int excl = sd2[t] - run;
        #pragma unroll
        for (int u = 0; u < 20; ++u) {
            int idx = t * 20 + u;
            if (idx < NODES_REAL) offs[idx] = excl + pre[u];
        }
        if (t == 255) offs[NODES_REAL] = excl + run;
    }
    tgt += NB; grid_sync(sync_cnt, tgt);

    // P2: scatter (grid-stride)
    for (int e = b * 256 + tid; e < Eh; e += (int)NB * 256) {
        int s = ei[e];
        int d = ei[Eh + e];
        int c = e >> 14;                   // e / CHUNK
        esrc[offs[d] + bases[c * NODES_REAL + d] + (int)rank16[e]] = (ushort_t)s;
    }
    tgt += NB; grid_sync(sync_cnt, tgt);

    // P3: agg layer 0 -> bufS (clobbers bases: dead now)
    for (int i = b; i < NODES_REAL; i += (int)NB)
        agg_dst(i, h2, sv, dv, offs, esrc, bs + 0 * D, bufS, gmaxu + 0, w, lane, tid, pair_l, red, lexs);
    tgt += NB; grid_sync(sync_cnt, tgt);

    // P4: gsmall layer 1 (hin = bufS)
    {
        int gw = b * 4 + w;
        if (gw * 16 < NODES_REAL)
            gsmall_wave(bufS, Wm + WT2_L, as_ + D, ad_ + D, h2, sv, dv, gmaxu + 1, gw * 16, lane);
    }
    tgt += NB; grid_sync(sync_cnt, tgt);

    // P5: agg layer 1 -> bufS
    for (int i = b; i < NODES_REAL; i += (int)NB)
        agg_dst(i, h2, sv, dv, offs, esrc, bs + D, bufS, gmaxu + 1, w, lane, tid, pair_l, red, lexs);
    tgt += NB; grid_sync(sync_cnt, tgt);

    // P6: gsmall layer 2 (hin = bufS)
    {
        int gw = b * 4 + w;
        if (gw * 16 < NODES_REAL)
            gsmall_wave(bufS, Wm + 2 * WT2_L, as_ + 2 * D, ad_ + 2 * D, h2, sv, dv, gmaxu + 2, gw * 16, lane);
    }
    tgt += NB; grid_sync(sync_cnt, tgt);

    // P7: agg layer 2 -> out (final)
    for (int i = b; i < NODES_REAL; i += (int)NB)
        agg_dst(i, h2, sv, dv, offs, esrc, bs + 2 * D, out, gmaxu + 2, w, lane, tid, pair_l, red, lexs);
}

// ---------------- launcher -----------------------------------------------------
extern "C" void kernel_launch(void* const* d_in, const int* in_sizes, int n_in,
                              void* d_out, int out_size, void* d_ws, size_t ws_size,
                              hipStream_t stream) {
    const float* x   = (const float*)d_in[0];
    const int*   ei  = (const int*)d_in[1];
    const float* Ws  = (const float*)d_in[2];
    const float* as_ = (const float*)d_in[3];
    const float* ad_ = (const float*)d_in[4];
    const float* bs  = (const float*)d_in[5];
    float* out = (float*)d_out;
    int Eh = in_sizes[1] / 2;                    // 1,280,000
    int nchunks = (Eh + CHUNK - 1) / CHUNK;      // 79

    char* ws = (char*)d_ws;
    float*    h2     = (float*)ws;                        //  2,560,000
    float*    bufS   = (float*)(ws + 2560000);            //  2,560,000 (also: bases)
    float*    sv     = (float*)(ws + 5120000);            //     20,000
    float*    dv     = (float*)(ws + 5140000);            //     20,000
    int*      counts = (int*)  (ws + 5160000);            //     20,000
    int*      offs   = (int*)  (ws + 5180000);            //     20,016
    ushort_t* rank16 = (ushort_t*)(ws + 5200016);         //  2,560,000
    ushort_t* esrc   = (ushort_t*)(ws + 7760016);         //  2,560,000
    ushort_t* Wm     = (ushort_t*)(ws + 10320016);        //    196,608 (frag-major)
    uint_t*   gmaxu  = (uint_t*)(ws + 10528912);          //         12
    uint_t*   sync_cnt = (uint_t*)(ws + 10528928);        //          4

    // 3 launches total (was 11): wsplit+zeros, mlp3, mega.
    wsplit_kernel<<<24, 256, 0, stream>>>(Ws, Wm, counts, gmaxu, sync_cnt);

    // rows >= 5000: fused 3-layer MLP, one HBM pass (r4-verified structure)
    mlp3_kernel<<<(NODES_TOTAL - NODES_REAL + 63) / 64, 256, 0, stream>>>(x, Wm, bs, out);

    // rows < 5000: CSR build + 3x(gsmall, agg) in one persistent kernel
    mega_kernel<<<MEGA_NB, 256, 0, stream>>>(x, Wm, as_, ad_, bs, ei, h2, bufS, sv, dv,
                                             counts, offs, rank16, esrc, gmaxu, out,
                                             sync_cnt, Eh, nchunks);
}

// Round 13
// 477.695 us; speedup vs baseline: 2.9923x; 2.9923x over previous
//
#include <hip/hip_runtime.h>
#include <math.h>

#define NODES_TOTAL 160000
#define NODES_REAL  5000
#define D 128
#define NEG 0.2f
#define KP2 128
#define HL2 (128 * KP2)       // ushorts per hi (or lo) block = 16384
#define WT2_L (2 * HL2)       // ushorts per layer (hi + lo)  = 32768 (64 KB)
#define CHUNK 16384           // edges per CSR chunk (2^14)

typedef unsigned short ushort_t;
typedef unsigned int uint_t;
typedef __attribute__((ext_vector_type(8))) __bf16 bf16x8;
typedef __attribute__((ext_vector_type(4))) float f32x4;
union BF8 { bf16x8 v; ushort_t u[8]; };

__device__ __forceinline__ void split2(float x, ushort_t& hi, ushort_t& lo) {
    unsigned u = __float_as_uint(x);
    hi = (ushort_t)(u >> 16);
    float hif = __uint_as_float(u & 0xffff0000u);
    lo = (ushort_t)(__float_as_uint(x - hif) >> 16);
}
__device__ __forceinline__ uint_t encmax(float f) {
    uint_t b = __float_as_uint(f);
    return b ^ ((uint_t)((int)b >> 31) | 0x80000000u);
}
__device__ __forceinline__ float decmax(uint_t u) {
    uint_t b = (u & 0x80000000u) ? (u ^ 0x80000000u) : ~u;
    return __uint_as_float(b);
}

// ---------------- W split (frag-major) + workspace zeroing ---------------------
__global__ void wsplit_kernel(const float* __restrict__ Ws, ushort_t* __restrict__ Wm,
                              int* __restrict__ counts, uint_t* __restrict__ gmaxu) {
    int gid = blockIdx.x * 256 + threadIdx.x;
    if (gid < NODES_REAL) counts[gid] = 0;
    if (gid < 3) gmaxu[gid] = 0u;
    int l  = blockIdx.x >> 3;
    int n  = (blockIdx.x & 7) * 16 + (threadIdx.x >> 4);
    int c8 = threadIdx.x & 15;
    int k0 = c8 * 8;
    const float* src = Ws + (size_t)l * D * D;
    union { ushort_t u[8]; uint4 v; } hi, lo;
    #pragma unroll
    for (int j = 0; j < 8; ++j) split2(src[(size_t)(k0 + j) * D + n], hi.u[j], lo.u[j]);
    int ct = n >> 4, m16 = n & 15, kc = c8 >> 2, qq = c8 & 3;
    int lane = qq * 16 + m16;
    ushort_t* d2 = Wm + (size_t)l * WT2_L + ((ct * 4 + kc) * 2 + 0) * 512 + lane * 8;
    *(uint4*)d2 = hi.v;
    *(uint4*)(d2 + 512) = lo.v;     // hl=1
}

// ---------------- device body: fused 3-layer MLP for one 64-row block ----------
__device__ __forceinline__ void mlp3_body(const float* __restrict__ x,
        const ushort_t* __restrict__ Wm, const float* __restrict__ bs,
        float* __restrict__ out, int row_base, int bid, int tid,
        float (*scr)[2][16][132]) {
    int w = tid >> 6, lane = tid & 63, q = lane >> 4, m16 = lane & 15;
    int p = w >> 1, h = w & 1;
    int row0 = row_base + bid * 64 + p * 32;

    float4 xa[2][4][2];
    #pragma unroll
    for (int rt = 0; rt < 2; ++rt) {
        int r = row0 + rt * 16 + m16;
        if (r > NODES_TOTAL - 1) r = NODES_TOTAL - 1;
        #pragma unroll
        for (int kc = 0; kc < 4; ++kc) {
            const float* gp = x + (size_t)r * D + kc * 32 + q * 8;
            xa[rt][kc][0] = *(const float4*)gp;
            xa[rt][kc][1] = *(const float4*)(gp + 4);
        }
    }

    f32x4 acc[2][4];
    #pragma unroll
    for (int l = 0; l < 3; ++l) {
        const ushort_t* Wml = Wm + (size_t)l * WT2_L;
        if (l > 0) __syncthreads();

        BF8 ahi[2][4], alo[2][4];
        #pragma unroll
        for (int rt = 0; rt < 2; ++rt)
            #pragma unroll
            for (int kc = 0; kc < 4; ++kc) {
                float4 v0, v1;
                if (l == 0) { v0 = xa[rt][kc][0]; v1 = xa[rt][kc][1]; }
                else {
                    const float* sp = &scr[p][rt][m16][kc * 32 + q * 8];
                    v0 = *(const float4*)sp; v1 = *(const float4*)(sp + 4);
                }
                float xv[8] = {v0.x, v0.y, v0.z, v0.w, v1.x, v1.y, v1.z, v1.w};
                #pragma unroll
                for (int j = 0; j < 8; ++j) split2(xv[j], ahi[rt][kc].u[j], alo[rt][kc].u[j]);
            }
        if (l > 0) __syncthreads();

        #pragma unroll
        for (int rt = 0; rt < 2; ++rt)
            #pragma unroll
            for (int ct = 0; ct < 4; ++ct) acc[rt][ct] = (f32x4){0.f, 0.f, 0.f, 0.f};

        #pragma unroll
        for (int ph = 0; ph < 2; ++ph) {
            int kc0 = ph * 2;
            bf16x8 bh[4][2], bl[4][2];
            #pragma unroll
            for (int ct = 0; ct < 4; ++ct)
                #pragma unroll
                for (int dk = 0; dk < 2; ++dk) {
                    const ushort_t* bp = Wml + (((h * 4 + ct) * 4 + (kc0 + dk)) * 2) * 512 + lane * 8;
                    bh[ct][dk] = *(const bf16x8*)bp;
                    bl[ct][dk] = *(const bf16x8*)(bp + 512);
                }
            #pragma unroll
            for (int dk = 0; dk < 2; ++dk)
                #pragma unroll
                for (int ct = 0; ct < 4; ++ct)
                    #pragma unroll
                    for (int rt = 0; rt < 2; ++rt) {
                        acc[rt][ct] = __builtin_amdgcn_mfma_f32_16x16x32_bf16(ahi[rt][kc0 + dk].v, bh[ct][dk], acc[rt][ct], 0, 0, 0);
                        acc[rt][ct] = __builtin_amdgcn_mfma_f32_16x16x32_bf16(ahi[rt][kc0 + dk].v, bl[ct][dk], acc[rt][ct], 0, 0, 0);
                        acc[rt][ct] = __builtin_amdgcn_mfma_f32_16x16x32_bf16(alo[rt][kc0 + dk].v, bh[ct][dk], acc[rt][ct], 0, 0, 0);
                    }
        }
        float bv[4];
        #pragma unroll
        for (int ct = 0; ct < 4; ++ct) bv[ct] = bs[l * D + (h * 4 + ct) * 16 + m16];
        #pragma unroll
        for (int rt = 0; rt < 2; ++rt)
            #pragma unroll
            for (int ct = 0; ct < 4; ++ct)
                #pragma unroll
                for (int reg = 0; reg < 4; ++reg)
                    scr[p][rt][q * 4 + reg][(h * 4 + ct) * 16 + m16] =
                        fmaxf(acc[rt][ct][reg] + bv[ct], 0.f);
    }
    __syncthreads();
    #pragma unroll
    for (int i = 0; i < 8; ++i) {
        int rowl = i * 2 + (lane >> 5);
        int grow = row0 + h * 16 + rowl;
        float4 v = *(const float4*)&scr[p][h][rowl][(lane & 31) * 4];
        if (grow < NODES_TOTAL)
            *(float4*)&out[(size_t)grow * D + (lane & 31) * 4] = v;
    }
}

// ---------------- device body: slim register-B gsmall (one wave, 16 rows) ------
__device__ __forceinline__ void gsmall_wave(const float* __restrict__ hin,
        const ushort_t* __restrict__ Wml, const float* __restrict__ a_s,
        const float* __restrict__ a_d, float* __restrict__ h2,
        float* __restrict__ sv, float* __restrict__ dv, uint_t* __restrict__ gmax,
        int row0, int lane) {
    int q = lane >> 4, m16 = lane & 15;
    int rr = row0 + m16; if (rr > NODES_REAL - 1) rr = NODES_REAL - 1;
    f32x4 acc[8];
    #pragma unroll
    for (int ct = 0; ct < 8; ++ct) acc[ct] = (f32x4){0.f, 0.f, 0.f, 0.f};
    #pragma unroll
    for (int kc = 0; kc < 4; ++kc) {
        const float* gp = hin + (size_t)rr * D + kc * 32 + q * 8;
        float4 v0 = *(const float4*)gp, v1 = *(const float4*)(gp + 4);
        BF8 ahi, alo;
        {
            float xv[8] = {v0.x, v0.y, v0.z, v0.w, v1.x, v1.y, v1.z, v1.w};
            #pragma unroll
            for (int j = 0; j < 8; ++j) split2(xv[j], ahi.u[j], alo.u[j]);
        }
        #pragma unroll
        for (int cth = 0; cth < 2; ++cth) {
            bf16x8 bh[4], bl[4];
            #pragma unroll
            for (int c4 = 0; c4 < 4; ++c4) {
                int ct = cth * 4 + c4;
                const ushort_t* bp = Wml + ((ct * 4 + kc) * 2) * 512 + lane * 8;
                bh[c4] = *(const bf16x8*)bp;
                bl[c4] = *(const bf16x8*)(bp + 512);
            }
            #pragma unroll
            for (int c4 = 0; c4 < 4; ++c4) {
                int ct = cth * 4 + c4;
                acc[ct] = __builtin_amdgcn_mfma_f32_16x16x32_bf16(ahi.v, bh[c4], acc[ct], 0, 0, 0);
                acc[ct] = __builtin_amdgcn_mfma_f32_16x16x32_bf16(ahi.v, bl[c4], acc[ct], 0, 0, 0);
                acc[ct] = __builtin_amdgcn_mfma_f32_16x16x32_bf16(alo.v, bh[c4], acc[ct], 0, 0, 0);
            }
        }
    }
    #pragma unroll
    for (int reg = 0; reg < 4; ++reg) {
        int grow = row0 + q * 4 + reg;
        if (grow < NODES_REAL) {
            #pragma unroll
            for (int ct = 0; ct < 8; ++ct)
                h2[(size_t)grow * D + ct * 16 + m16] = acc[ct][reg];
        }
    }
    float asv[8], adv[8];
    #pragma unroll
    for (int ct = 0; ct < 8; ++ct) { asv[ct] = a_s[ct * 16 + m16]; adv[ct] = a_d[ct * 16 + m16]; }
    #pragma unroll
    for (int reg = 0; reg < 4; ++reg) {
        float ps = 0.f, pd = 0.f;
        #pragma unroll
        for (int ct = 0; ct < 8; ++ct) {
            float v = acc[ct][reg];
            ps += v * asv[ct]; pd += v * adv[ct];
        }
        #pragma unroll
        for (int o = 1; o < 16; o <<= 1) { ps += __shfl_xor(ps, o); pd += __shfl_xor(pd, o); }
        int grow = row0 + q * 4 + reg;
        if (m16 == 0 && grow < NODES_REAL) {
            sv[grow] = ps; dv[grow] = pd;
            atomicMax(gmax, encmax(ps));
        }
    }
}

// ---------------- device body: shfl-free 2-phase agg for one dst ---------------
__device__ __forceinline__ void agg_dst(int i, const float* __restrict__ h2,
        const float* __restrict__ sv, const float* __restrict__ dv,
        const int* __restrict__ offs, const ushort_t* __restrict__ esrc,
        const float* __restrict__ bias, float* __restrict__ hout,
        const uint_t* __restrict__ gmaxu, int w, int lane, int tid,
        float2* pair_l, float2 (*red)[64], float* lexs) {
    int start = offs[i], end = offs[i + 1];
    float d_i = dv[i];
    float gm = decmax(*gmaxu) + d_i;
    float m = gm > 0.f ? gm : NEG * gm;
    const float2* h2v = (const float2*)h2;
    float ax0 = 0.f, ay0 = 0.f, ax1 = 0.f, ay1 = 0.f;
    float ax2 = 0.f, ay2 = 0.f, ax3 = 0.f, ay3 = 0.f, exs = 0.f;
    for (int tile = start; tile < end; tile += 512) {
        int tcnt = min(512, end - tile);
        __syncthreads();
        #pragma unroll
        for (int hh = 0; hh < 2; ++hh) {
            int j = hh * 256 + tid;
            if (j < tcnt) {
                int s = (int)esrc[tile + j];
                float sc = sv[s] + d_i;
                sc = sc > 0.f ? sc : NEG * sc;
                float ex = __expf(sc - m);
                exs += ex;
                pair_l[j] = make_float2(ex, __uint_as_float((uint_t)s));
            }
        }
        __syncthreads();
        for (int j0 = w * 64; j0 < tcnt; j0 += 256) {
            int jend = min(j0 + 64, tcnt);
            int j = j0;
            for (; j + 4 <= jend; j += 4) {
                float2 p0 = pair_l[j],     p1 = pair_l[j + 1];
                float2 p2 = pair_l[j + 2], p3 = pair_l[j + 3];
                float2 v0 = h2v[(size_t)__float_as_uint(p0.y) * 64 + lane];
                float2 v1 = h2v[(size_t)__float_as_uint(p1.y) * 64 + lane];
                float2 v2 = h2v[(size_t)__float_as_uint(p2.y) * 64 + lane];
                float2 v3 = h2v[(size_t)__float_as_uint(p3.y) * 64 + lane];
                ax0 += p0.x * v0.x; ay0 += p0.x * v0.y;
                ax1 += p1.x * v1.x; ay1 += p1.x * v1.y;
                ax2 += p2.x * v2.x; ay2 += p2.x * v2.y;
                ax3 += p3.x * v3.x; ay3 += p3.x * v3.y;
            }
            for (; j < jend; ++j) {
                float2 p0 = pair_l[j];
                float2 v0 = h2v[(size_t)__float_as_uint(p0.y) * 64 + lane];
                ax0 += p0.x * v0.x; ay0 += p0.x * v0.y;
            }
        }
    }
    float ax = (ax0 + ax1) + (ax2 + ax3);
    float ay = (ay0 + ay1) + (ay2 + ay3);
    #pragma unroll
    for (int o = 1; o < 64; o <<= 1) exs += __shfl_xor(exs, o);
    __syncthreads();
    red[w][lane] = make_float2(ax, ay);
    if (lane == 0) lexs[w] = exs;
    __syncthreads();
    if (w == 0) {
        float2 r1 = red[1][lane], r2 = red[2][lane], r3 = red[3][lane];
        ax += r1.x + r2.x + r3.x;
        ay += r1.y + r2.y + r3.y;
        float exst = lexs[0] + lexs[1] + lexs[2] + lexs[3];
        float scf = sv[i] + d_i; scf = scf > 0.f ? scf : NEG * scf;
        float exf = __expf(scf - m);
        float2 hv = h2v[(size_t)i * 64 + lane];
        ax += exf * hv.x; ay += exf * hv.y;
        float rd = 1.f / (exst + exf);
        float2 b2 = *(const float2*)&bias[2 * lane];
        float2 o2 = make_float2(fmaxf(ax * rd + b2.x, 0.f), fmaxf(ay * rd + b2.y, 0.f));
        *(float2*)&hout[(size_t)i * D + 2 * lane] = o2;
    }
}

// ---------------- launch 2: rank2 (blocks<nchunks) || gsmall layer0 ------------
__global__ __launch_bounds__(256, 4)
void comboA_kernel(const int* __restrict__ ei, int* __restrict__ counts,
                   int* __restrict__ bases, ushort_t* __restrict__ rank16,
                   int Eh, int nchunks,
                   const float* __restrict__ x, const ushort_t* __restrict__ Wm,
                   const float* __restrict__ as_, const float* __restrict__ ad_,
                   float* __restrict__ h2, float* __restrict__ sv,
                   float* __restrict__ dv, uint_t* __restrict__ gmaxu) {
    __shared__ uint_t lc[NODES_REAL];      // 20 KB (rank2 path only)
    int b = blockIdx.x, tid = threadIdx.x;
    if (b < nchunks) {
        for (int i2 = tid; i2 < NODES_REAL; i2 += 256) lc[i2] = 0u;
        __syncthreads();
        int e0 = b * CHUNK;
        #pragma unroll 4
        for (int k = 0; k < CHUNK / 256; ++k) {
            int e = e0 + k * 256 + tid;
            if (e < Eh) {
                int d = ei[Eh + e];
                uint_t r = atomicAdd(&lc[d], 1u);
                rank16[e] = (ushort_t)r;
            }
        }
        __syncthreads();
        for (int i2 = tid; i2 < NODES_REAL; i2 += 256) {
            uint_t n = lc[i2];
            if (n > 0u)
                bases[b * NODES_REAL + i2] = atomicAdd(&counts[i2], (int)n);
        }
    } else {
        int gw = (b - nchunks) * 4 + (tid >> 6);
        if (gw * 16 < NODES_REAL)
            gsmall_wave(x, Wm, as_, ad_, h2, sv, dv, gmaxu + 0, gw * 16, tid & 63);
    }
}

__global__ void scan_kernel(const int* __restrict__ counts, int* __restrict__ offs) {
    __shared__ int sd[1024];
    int t = threadIdx.x;
    int pre[5]; int sum = 0;
    #pragma unroll
    for (int u = 0; u < 5; ++u) {
        int idx = t * 5 + u;
        int c = (idx < NODES_REAL) ? counts[idx] : 0;
        pre[u] = sum; sum += c;
    }
    sd[t] = sum;
    __syncthreads();
    int run = sum;
    for (int o = 1; o < 1024; o <<= 1) {
        int v = (t >= o) ? sd[t - o] : 0;
        __syncthreads();
        sd[t] += v;
        __syncthreads();
    }
    int excl = sd[t] - run;
    #pragma unroll
    for (int u = 0; u < 5; ++u) {
        int idx = t * 5 + u;
        if (idx < NODES_REAL) offs[idx] = excl + pre[u];
    }
    if (t == 1023) offs[NODES_REAL] = excl + run;
}

__global__ void scatter_det(const int* __restrict__ ei, const int* __restrict__ offs,
                            const int* __restrict__ bases,
                            const ushort_t* __restrict__ rank16, ushort_t* __restrict__ esrc,
                            int Eh) {
    int e = blockIdx.x * blockDim.x + threadIdx.x;
    if (e < Eh) {
        int s = ei[e];
        int d = ei[Eh + e];
        int c = e >> 14;                   // e / CHUNK
        esrc[offs[d] + bases[c * NODES_REAL + d] + (int)rank16[e]] = (ushort_t)s;
    }
}

// ---------------- combo: mlp3 slice (blocks < mlp_nb) || agg layer -------------
// agg is latency-bound (HBM 3%, VALU 22%, MFMA 0) -> mlp3 blocks fill the idle
// pipes of the same launch for free (co-resident waves: time ~ max, not sum).
__global__ __launch_bounds__(256, 2)
void combo_kernel(const float* __restrict__ x, const ushort_t* __restrict__ Wm,
                  const float* __restrict__ bs, float* __restrict__ out,
                  int mlp_nb, int mlp_row_base,
                  const float* __restrict__ h2, const float* __restrict__ sv,
                  const float* __restrict__ dv, const int* __restrict__ offs,
                  const ushort_t* __restrict__ esrc, const float* __restrict__ bias_l,
                  float* __restrict__ hout, const uint_t* __restrict__ gmaxu_l) {
    __shared__ float scr[2][2][16][132];   // 33792 B (mlp3 path)
    __shared__ float2 pair_l[512];         //  4096 B (agg path)
    __shared__ float2 red[4][64];          //  2048 B
    __shared__ float lexs[4];
    int b = blockIdx.x, tid = threadIdx.x;
    if (b < mlp_nb) {
        mlp3_body(x, Wm, bs, out, mlp_row_base, b, tid, scr);
    } else {
        int i = b - mlp_nb;                // 0..NODES_REAL-1
        agg_dst(i, h2, sv, dv, offs, esrc, bias_l, hout, gmaxu_l,
                tid >> 6, tid & 63, tid, pair_l, red, lexs);
    }
}

// ---------------- standalone gsmall for layers 1,2 (64-thr, register-B) --------
__global__ __launch_bounds__(64, 2)
void gsmall_kernel(const float* __restrict__ hin, const ushort_t* __restrict__ Wm,
                   const float* __restrict__ a_s, const float* __restrict__ a_d,
                   float* __restrict__ h2, float* __restrict__ sv, float* __restrict__ dv,
                   uint_t* __restrict__ gmaxu) {
    gsmall_wave(hin, Wm, a_s, a_d, h2, sv, dv, gmaxu, blockIdx.x * 16, threadIdx.x & 63);
}

// ---------------- launcher -----------------------------------------------------
extern "C" void kernel_launch(void* const* d_in, const int* in_sizes, int n_in,
                              void* d_out, int out_size, void* d_ws, size_t ws_size,
                              hipStream_t stream) {
    const float* x   = (const float*)d_in[0];
    const int*   ei  = (const int*)d_in[1];
    const float* Ws  = (const float*)d_in[2];
    const float* as_ = (const float*)d_in[3];
    const float* ad_ = (const float*)d_in[4];
    const float* bs  = (const float*)d_in[5];
    float* out = (float*)d_out;
    int Eh = in_sizes[1] / 2;                    // 1,280,000
    int nchunks = (Eh + CHUNK - 1) / CHUNK;      // 79

    char* ws = (char*)d_ws;
    float*    h2     = (float*)ws;                        //  2,560,000
    float*    bufS   = (float*)(ws + 2560000);            //  2,560,000 (also: bases)
    float*    sv     = (float*)(ws + 5120000);            //     20,000
    float*    dv     = (float*)(ws + 5140000);            //     20,000
    int*      counts = (int*)  (ws + 5160000);            //     20,000
    int*      offs   = (int*)  (ws + 5180000);            //     20,016
    ushort_t* rank16 = (ushort_t*)(ws + 5200016);         //  2,560,000
    ushort_t* esrc   = (ushort_t*)(ws + 7760016);         //  2,560,000
    ushort_t* Wm     = (ushort_t*)(ws + 10320016);        //    196,608 (frag-major)
    uint_t*   gmaxu  = (uint_t*)(ws + 10528912);          //         12
    int*      bases  = (int*)bufS;  // 79*5000*4 = 1.58MB, dead until agg0 writes bufS

    const int MLP_NB = (NODES_TOTAL - NODES_REAL + 63) / 64;   // 2422
    const int S0 = 808, S1 = 808, S2 = MLP_NB - S0 - S1;       // 808+808+806

    // 9 launches (was 11; mlp3's 96us absorbed into the 3 agg launches):
    wsplit_kernel<<<24, 256, 0, stream>>>(Ws, Wm, counts, gmaxu);
    comboA_kernel<<<nchunks + (NODES_REAL + 63) / 64, 256, 0, stream>>>(
        ei, counts, bases, rank16, Eh, nchunks, x, Wm, as_, ad_, h2, sv, dv, gmaxu);
    scan_kernel<<<1, 1024, 0, stream>>>(counts, offs);
    scatter_det<<<(Eh + 255) / 256, 256, 0, stream>>>(ei, offs, bases, rank16, esrc, Eh);

    // layer 0 agg || mlp3 slice 0   (agg0 -> bufS, clobbers bases: scatter done)
    combo_kernel<<<S0 + NODES_REAL, 256, 0, stream>>>(
        x, Wm, bs, out, S0, NODES_REAL + 0 * 64,
        h2, sv, dv, offs, esrc, bs + 0 * D, bufS, gmaxu + 0);
    gsmall_kernel<<<(NODES_REAL + 15) / 16, 64, 0, stream>>>(
        bufS, Wm + WT2_L, as_ + D, ad_ + D, h2, sv, dv, gmaxu + 1);
    // layer 1 agg || mlp3 slice 1
    combo_kernel<<<S1 + NODES_REAL, 256, 0, stream>>>(
        x, Wm, bs, out, S1, NODES_REAL + S0 * 64,
        h2, sv, dv, offs, esrc, bs + 1 * D, bufS, gmaxu + 1);
    gsmall_kernel<<<(NODES_REAL + 15) / 16, 64, 0, stream>>>(
        bufS, Wm + 2 * WT2_L, as_ + 2 * D, ad_ + 2 * D, h2, sv, dv, gmaxu + 2);
    // layer 2 agg || mlp3 slice 2   (agg2 -> out rows <5000; mlp3 -> rows >=5000)
    combo_kernel<<<S2 + NODES_REAL, 256, 0, stream>>>(
        x, Wm, bs, out, S2, NODES_REAL + (S0 + S1) * 64,
        h2, sv, dv, offs, esrc, bs + 2 * D, out, gmaxu + 2);
}